// Round 14
// baseline (107.185 us; speedup 1.0000x reference)
//
#include <hip/hip_runtime.h>
#include <hip/hip_bf16.h>
#include <math.h>

#define MDIM 128
#define CDIM 64
#define NTILES 1366   // 16-key MFMA tiles: d1:1 d2:1 d3:4 d4:16 d5:64 d6:256 d7:1024
// tile blk index: d1=0, d2=1, d3=2+T3, d4=6+T4, d5=22+S5, d6=86+T6, d7=342+T7

typedef __attribute__((ext_vector_type(8))) __bf16 bf16x8;
typedef __attribute__((ext_vector_type(4))) float f32x4;

// ---------------------------------------------------------------------------
// K0: convert Wk (7x128x128 f32) -> bf16 once.
// ---------------------------------------------------------------------------
__global__ __launch_bounds__(256) void k_cvtw(const float* __restrict__ Wk,
                                              __hip_bfloat16* __restrict__ wkb) {
  const int i = blockIdx.x * 256 + threadIdx.x;   // one float4 per thread
  float4 v = *reinterpret_cast<const float4*>(Wk + (size_t)i * 4);
  __hip_bfloat16 h[4];
  h[0] = __float2bfloat16(v.x); h[1] = __float2bfloat16(v.y);
  h[2] = __float2bfloat16(v.z); h[3] = __float2bfloat16(v.w);
  unsigned long long bits;
  __builtin_memcpy(&bits, h, 8);
  *reinterpret_cast<unsigned long long*>(wkb + (size_t)i * 4) = bits;
}

// ---------------------------------------------------------------------------
// K1: keys via MFMA, output in FRAGMENT ORDER.
// ---------------------------------------------------------------------------
#define STR 144   // sT row stride in bf16 (16B-aligned rows)

__global__ __launch_bounds__(64) void k_keys_mfma(const float* __restrict__ states,
                                                  const __hip_bfloat16* __restrict__ wkb,
                                                  const float* __restrict__ bk,
                                                  bf16x8* __restrict__ keysF) {
  __shared__ __align__(16) __hip_bfloat16 sT[16 * STR];  // [key c][m]
  const int lane = threadIdx.x;
  const int c = lane & 15, hi = lane >> 4;
  int blk = blockIdx.x, d, t;
  if      (blk < 2)   { d = blk; t = 0; }
  else if (blk < 6)   { d = 2; t = blk - 2; }
  else if (blk < 22)  { d = 3; t = blk - 6; }
  else if (blk < 86)  { d = 4; t = blk - 22; }
  else if (blk < 342) { d = 5; t = blk - 86; }
  else                { d = 6; t = blk - 342; }
  const int cumArr[7] = {0, 4, 20, 84, 340, 1364, 5460};
  const int k0 = cumArr[d] + 16 * t;

  bf16x8 sb[4];
  const float* srow = states + (size_t)(k0 + c) * MDIM;
#pragma unroll
  for (int kf = 0; kf < 4; ++kf) {
    float4 a = *reinterpret_cast<const float4*>(srow + kf * 32 + hi * 8);
    float4 b = *reinterpret_cast<const float4*>(srow + kf * 32 + hi * 8 + 4);
    bf16x8 v;
    v[0] = (__bf16)a.x; v[1] = (__bf16)a.y; v[2] = (__bf16)a.z; v[3] = (__bf16)a.w;
    v[4] = (__bf16)b.x; v[5] = (__bf16)b.y; v[6] = (__bf16)b.z; v[7] = (__bf16)b.w;
    sb[kf] = v;
  }

  const __hip_bfloat16* wkd = wkb + (size_t)d * MDIM * MDIM;
  const float* bkd = bk + d * MDIM;

#pragma unroll
  for (int ct = 0; ct < 8; ++ct) {
    bf16x8 aw[4];
    const __hip_bfloat16* wrow = wkd + (size_t)(ct * 16 + c) * MDIM;
#pragma unroll
    for (int kf = 0; kf < 4; ++kf)
      aw[kf] = *reinterpret_cast<const bf16x8*>(wrow + kf * 32 + hi * 8);
    f32x4 acc = {};
#pragma unroll
    for (int kf = 0; kf < 4; ++kf)
      acc = __builtin_amdgcn_mfma_f32_16x16x32_bf16(aw[kf], sb[kf], acc, 0, 0, 0);
    float4 bias = *reinterpret_cast<const float4*>(bkd + ct * 16 + hi * 4);
    __hip_bfloat16 hv[4];
    hv[0] = __float2bfloat16(fmaxf(acc[0] + bias.x, 0.f));
    hv[1] = __float2bfloat16(fmaxf(acc[1] + bias.y, 0.f));
    hv[2] = __float2bfloat16(fmaxf(acc[2] + bias.z, 0.f));
    hv[3] = __float2bfloat16(fmaxf(acc[3] + bias.w, 0.f));
    unsigned long long bits;
    __builtin_memcpy(&bits, hv, 8);
    *reinterpret_cast<unsigned long long*>(&sT[c * STR + ct * 16 + 4 * hi]) = bits;
  }

#pragma unroll
  for (int kf = 0; kf < 4; ++kf) {
    bf16x8 v = *reinterpret_cast<const bf16x8*>(&sT[c * STR + kf * 32 + hi * 8]);
    keysF[(size_t)(blk * 4 + kf) * 64 + lane] = v;   // 64 lanes x 16B = 1KB
  }
}

// ---------------------------------------------------------------------------
// K2: query via MFMA. One wave per 16 b rows: D = Wq * hidden^T (+bq).
// A = Wq rows (m), B = hidden rows (b); inline f32->bf16; LDS repack to
// row-major query[b][m] (same pattern as k_keys_mfma).
// ---------------------------------------------------------------------------
__global__ __launch_bounds__(64) void k_query_mfma(const float* __restrict__ hidden,
                                                   const float* __restrict__ Wq,
                                                   const float* __restrict__ bq,
                                                   __hip_bfloat16* __restrict__ query) {
  __shared__ __align__(16) __hip_bfloat16 sT[16 * STR];  // [b c][m]
  const int lane = threadIdx.x;
  const int c = lane & 15, hi = lane >> 4;
  const int b0 = blockIdx.x * 16;

  // B-frags: hidden rows (K=64 -> 2 chunks), f32 -> bf16 inline
  bf16x8 hb[2];
  const float* hrow = hidden + (size_t)(b0 + c) * CDIM;
#pragma unroll
  for (int kf = 0; kf < 2; ++kf) {
    float4 a = *reinterpret_cast<const float4*>(hrow + kf * 32 + hi * 8);
    float4 b = *reinterpret_cast<const float4*>(hrow + kf * 32 + hi * 8 + 4);
    bf16x8 v;
    v[0] = (__bf16)a.x; v[1] = (__bf16)a.y; v[2] = (__bf16)a.z; v[3] = (__bf16)a.w;
    v[4] = (__bf16)b.x; v[5] = (__bf16)b.y; v[6] = (__bf16)b.z; v[7] = (__bf16)b.w;
    hb[kf] = v;
  }

#pragma unroll
  for (int ct = 0; ct < 8; ++ct) {
    const float* wrow = Wq + (size_t)(ct * 16 + c) * CDIM;
    f32x4 acc = {};
#pragma unroll
    for (int kf = 0; kf < 2; ++kf) {
      float4 a = *reinterpret_cast<const float4*>(wrow + kf * 32 + hi * 8);
      float4 b = *reinterpret_cast<const float4*>(wrow + kf * 32 + hi * 8 + 4);
      bf16x8 v;
      v[0] = (__bf16)a.x; v[1] = (__bf16)a.y; v[2] = (__bf16)a.z; v[3] = (__bf16)a.w;
      v[4] = (__bf16)b.x; v[5] = (__bf16)b.y; v[6] = (__bf16)b.z; v[7] = (__bf16)b.w;
      acc = __builtin_amdgcn_mfma_f32_16x16x32_bf16(v, hb[kf], acc, 0, 0, 0);
    }
    float4 bias = *reinterpret_cast<const float4*>(bq + ct * 16 + hi * 4);
    __hip_bfloat16 hv[4];
    hv[0] = __float2bfloat16(acc[0] + bias.x);
    hv[1] = __float2bfloat16(acc[1] + bias.y);
    hv[2] = __float2bfloat16(acc[2] + bias.z);
    hv[3] = __float2bfloat16(acc[3] + bias.w);
    unsigned long long bits;
    __builtin_memcpy(&bits, hv, 8);
    *reinterpret_cast<unsigned long long*>(&sT[c * STR + ct * 16 + 4 * hi]) = bits;
  }

#pragma unroll
  for (int kf = 0; kf < 4; ++kf) {
    bf16x8 v = *reinterpret_cast<const bf16x8*>(&sT[c * STR + kf * 32 + hi * 8]);
    *reinterpret_cast<bf16x8*>(query + (size_t)(b0 + c) * MDIM + kf * 32 + hi * 8) = v;
  }
}

// ---------------------------------------------------------------------------
// K3: subtree walker, v14 — block = 4 waves x same 32 b x 4 consecutive
// subtrees (S5 = 4*chunk + w). Block owns 64 consecutive d5 keys -> d5 goes
// through a block-shared LDS buffer (flushed once at kernel end as 256B
// full-line b-rows, one __syncthreads). d6/d7 buffers per-wave as in v13.
// Frag-ordered keys straight to registers; no-max softmax; shuffle parent.
// ---------------------------------------------------------------------------
#define D7STR 68   // padded row stride (floats)

struct Frag { bf16x8 f[4]; };

__device__ __forceinline__ void load_frags(const bf16x8* __restrict__ kF,
                                           int blk, Frag& fr, int lane) {
#pragma unroll
  for (int kf = 0; kf < 4; ++kf)
    fr.f[kf] = kF[(size_t)(blk * 4 + kf) * 64 + lane];
}

__device__ __forceinline__ float gather_par(const f32x4 cp, int u, int lane) {
  const int src = u * 16 + (lane & 15);
  const float g0 = __shfl(cp[0], src, 64);
  const float g1 = __shfl(cp[1], src, 64);
  const float g2 = __shfl(cp[2], src, 64);
  const float g3 = __shfl(cp[3], src, 64);
  const int hi = lane >> 4;
  const float p01 = (hi & 1) ? g1 : g0;
  const float p23 = (hi & 1) ? g3 : g2;
  return (hi & 2) ? p23 : p01;
}

__device__ __forceinline__ void tile_step(
    const bf16x8* __restrict__ kF, const Frag& cur, int nextBlk, Frag& nxt,
    const bf16x8 (&qf)[2][4], const f32x4* cumPrev, int u, f32x4 (&cumOut)[2],
    float* __restrict__ oPtr, size_t span, bool doStore, bool d1mask,
    float* __restrict__ ldsDst, int lane) {
  const int c = lane & 15, hi = lane >> 4;

  // prefetch next tile's frags (L2 latency hides under this tile's compute)
  if (nextBlk >= 0) load_frags(kF, nextBlk, nxt, lane);

#pragma unroll
  for (int bt = 0; bt < 2; ++bt) {
    f32x4 acc = {};
    acc = __builtin_amdgcn_mfma_f32_16x16x32_bf16(cur.f[0], qf[bt][0], acc, 0, 0, 0);
    acc = __builtin_amdgcn_mfma_f32_16x16x32_bf16(cur.f[1], qf[bt][1], acc, 0, 0, 0);
    acc = __builtin_amdgcn_mfma_f32_16x16x32_bf16(cur.f[2], qf[bt][2], acc, 0, 0, 0);
    acc = __builtin_amdgcn_mfma_f32_16x16x32_bf16(cur.f[3], qf[bt][3], acc, 0, 0, 0);

    // group-of-4 log-softmax without max-subtraction (scores bounded)
    const float lse = __logf(__expf(acc[0]) + __expf(acc[1]) +
                             __expf(acc[2]) + __expf(acc[3]));
    float par = 0.f;
    if (cumPrev) par = gather_par(cumPrev[bt], u, lane);
    f32x4 cm;
    cm[0] = acc[0] - lse + par;
    cm[1] = acc[1] - lse + par;
    cm[2] = acc[2] - lse + par;
    cm[3] = acc[3] - lse + par;
    cumOut[bt] = cm;

    if (ldsDst) {
      *reinterpret_cast<f32x4*>(ldsDst + (bt * 16 + c) * D7STR) = cm;
    } else if (doStore && (!d1mask || hi == 0)) {
      float4 o;
      o.x = cm[0]; o.y = cm[1]; o.z = cm[2]; o.w = cm[3];
      *reinterpret_cast<float4*>(oPtr + (size_t)(bt * 16 + c) * span + hi * 4) = o;
    }
  }
}

__global__ __launch_bounds__(256) void k_tree(const bf16x8* __restrict__ kF,
                                              const __hip_bfloat16* __restrict__ query,
                                              float* __restrict__ out, int B) {
  __shared__ __align__(16) float sD7[4][32 * D7STR]; // per-wave d6-group buffer
  __shared__ __align__(16) float sD6[4][32 * D7STR]; // per-wave d6 subtree buffer
  __shared__ __align__(16) float sD5[32 * D7STR];    // block-shared d5 buffer

  const int tid  = threadIdx.x;
  const int lane = tid & 63;
  const int w    = tid >> 6;
  const int c    = lane & 15, hi = lane >> 4;

  const int chunk = blockIdx.x & 15;      // 4-subtree chunk (XCD = chunk%8)
  const int bg    = blockIdx.x >> 4;      // batch group (32 b per block)
  const int S5    = 4 * chunk + w;        // this wave's subtree
  const int T4    = chunk;
  const int T3    = chunk >> 2;
  const int b0w   = bg * 32;              // block-shared 32-b base

  float* d7w = &sD7[w][0];
  float* d6w = &sD6[w][0];

  // query B-frags for both b-tiles (held in regs for all tiles)
  bf16x8 qf[2][4];
#pragma unroll
  for (int bt = 0; bt < 2; ++bt) {
    const __hip_bfloat16* qrow = query + (size_t)(b0w + bt * 16 + c) * MDIM;
#pragma unroll
    for (int kf = 0; kf < 4; ++kf)
      qf[bt][kf] = *reinterpret_cast<const bf16x8*>(qrow + kf * 32 + hi * 8);
  }

  Frag fA, fB;
  load_frags(kF, 0, fA, lane);            // d1 tile

  f32x4 c1[2], c2[2], c3[2], c4[2], c5[2], c6[2], c7[2];
  const bool w0 = (w == 0);

  // d1 (blk 0): next d2 (blk 1)
  tile_step(kF, fA, 1, fB, qf, nullptr, 0, c1,
            out + (size_t)b0w * 4, 4, chunk == 0 && w0, true, nullptr, lane);
  // d2: next d3
  tile_step(kF, fB, 2 + T3, fA, qf, c1, 0, c2,
            out + (size_t)4 * B + (size_t)b0w * 16, 16, chunk == 0 && w0, false,
            nullptr, lane);
  // d3: next d4
  tile_step(kF, fA, 6 + T4, fB, qf, c2, T3, c3,
            out + (size_t)20 * B + (size_t)b0w * 64 + 16 * T3, 64,
            (chunk & 3) == 0 && w0, false, nullptr, lane);
  // d4: next d5 (this wave's subtree)
  tile_step(kF, fB, 22 + S5, fA, qf, c3, T4 & 3, c4,
            out + (size_t)84 * B + (size_t)b0w * 256 + 16 * T4, 256,
            w0, false, nullptr, lane);
  // d5: buffered in block-shared sD5 at col w*16; parent quad = w
  tile_step(kF, fA, 86 + 4 * S5, fB, qf, c4, w, c5,
            nullptr, 0, false, false, &sD5[0] + w * 16 + hi * 4, lane);

  // d6/d7 groups. Each group = 5 tile_steps; frag parity flips per group.
#pragma unroll
  for (int u5p = 0; u5p < 2; ++u5p) {
#pragma unroll
    for (int half = 0; half < 2; ++half) {
      const int u5 = u5p * 2 + half;
      Frag& f0 = (half == 0) ? fB : fA;   // compile-time after unroll
      Frag& f1 = (half == 0) ? fA : fB;
      const int T6 = 4 * S5 + u5;
      const int d7b = 342 + 16 * S5 + 4 * u5;   // first d7 blk of this group
      // d6: buffered in sD6 (col u5*16), flushed after the u5 loop
      tile_step(kF, f0, d7b, f1, qf, c5, u5, c6,
                nullptr, 0, false, false, d6w + u5 * 16 + hi * 4, lane);
      // d7 u6=0..3
      tile_step(kF, f1, d7b + 1, f0, qf, c6, 0, c7,
                nullptr, 0, false, false, d7w + 0 * 16 + hi * 4, lane);
      tile_step(kF, f0, d7b + 2, f1, qf, c6, 1, c7,
                nullptr, 0, false, false, d7w + 1 * 16 + hi * 4, lane);
      tile_step(kF, f1, d7b + 3, f0, qf, c6, 2, c7,
                nullptr, 0, false, false, d7w + 2 * 16 + hi * 4, lane);
      tile_step(kF, f0, (u5 < 3) ? (86 + 4 * S5 + u5 + 1) : -1, f1, qf, c6, 3, c7,
                nullptr, 0, false, false, d7w + 3 * 16 + hi * 4, lane);
      // flush d6-group T6's d7: 32 b-rows; 8 instrs x 4 rows x 256B runs
      {
        float* dst = out + (size_t)5460 * B + (size_t)b0w * 16384 + 64 * T6;
#pragma unroll
        for (int j = 0; j < 8; ++j) {
          const int r = j * 4 + hi;
          f32x4 v = *reinterpret_cast<const f32x4*>(d7w + r * D7STR + c * 4);
          float4 o;
          o.x = v[0]; o.y = v[1]; o.z = v[2]; o.w = v[3];
          *reinterpret_cast<float4*>(dst + (size_t)r * 16384 + c * 4) = o;
        }
      }
    }
  }

  // flush d6 for this wave's subtree: 32 b-rows x 64 keys; 8 x 256B runs
  {
    float* dst = out + (size_t)1364 * B + (size_t)b0w * 4096 + 64 * S5;
#pragma unroll
    for (int j = 0; j < 8; ++j) {
      const int r = j * 4 + hi;
      f32x4 v = *reinterpret_cast<const f32x4*>(d6w + r * D7STR + c * 4);
      float4 o;
      o.x = v[0]; o.y = v[1]; o.z = v[2]; o.w = v[3];
      *reinterpret_cast<float4*>(dst + (size_t)r * 4096 + c * 4) = o;
    }
  }

  // flush d5 for the whole block (64 consecutive keys x 32 b): 256B runs
  __syncthreads();
  {
    float* dst = out + (size_t)340 * B + (size_t)b0w * 1024 + 64 * chunk;
    const int r16 = tid >> 4, c16 = tid & 15;
#pragma unroll
    for (int j = 0; j < 2; ++j) {
      const int r = j * 16 + r16;
      f32x4 v = *reinterpret_cast<const f32x4*>(&sD5[0] + r * D7STR + c16 * 4);
      float4 o;
      o.x = v[0]; o.y = v[1]; o.z = v[2]; o.w = v[3];
      *reinterpret_cast<float4*>(dst + (size_t)r * 1024 + c16 * 4) = o;
    }
  }
}

// ---------------------------------------------------------------------------
extern "C" void kernel_launch(void* const* d_in, const int* in_sizes, int n_in,
                              void* d_out, int out_size, void* d_ws, size_t ws_size,
                              hipStream_t stream) {
  const float* hidden = (const float*)d_in[0];
  const float* Wq     = (const float*)d_in[1];
  const float* bq     = (const float*)d_in[2];
  const float* states = (const float*)d_in[3];
  const float* Wk     = (const float*)d_in[4];
  const float* bk     = (const float*)d_in[5];
  float* out = (float*)d_out;
  const int B = in_sizes[0] / CDIM;  // 4096

  __hip_bfloat16* base  = (__hip_bfloat16*)d_ws;
  bf16x8* keysF = (bf16x8*)base;                              // 5.6MB frag-ordered
  __hip_bfloat16* query = base + (size_t)NTILES * 4 * 64 * 8; // B*128 bf16
  __hip_bfloat16* wkb   = query + (size_t)B * MDIM;           // 7*128*128 bf16

  k_cvtw<<<(7 * MDIM * MDIM) / (256 * 4), 256, 0, stream>>>(Wk, wkb);
  k_query_mfma<<<B / 16, 64, 0, stream>>>(hidden, Wq, bq, query);
  k_keys_mfma<<<NTILES, 64, 0, stream>>>(states, wkb, bk, keysF);

  // grid: chunk-fastest (XCD pinning): 16 chunks x B/32 batch groups
  k_tree<<<(B / 32) * 16, 256, 0, stream>>>(keysF, query, out, B);
}

// Round 15
// 100.806 us; speedup vs baseline: 1.0633x; 1.0633x over previous
//
#include <hip/hip_runtime.h>
#include <hip/hip_bf16.h>
#include <math.h>

#define MDIM 128
#define CDIM 64
#define NTILES 1366   // 16-key MFMA tiles: d1:1 d2:1 d3:4 d4:16 d5:64 d6:256 d7:1024
// tile blk index: d1=0, d2=1, d3=2+T3, d4=6+T4, d5=22+S5, d6=86+T6, d7=342+T7

typedef __attribute__((ext_vector_type(8))) __bf16 bf16x8;
typedef __attribute__((ext_vector_type(4))) float f32x4;

#define STR 144   // sT row stride in bf16 (16B-aligned rows)

__device__ __forceinline__ bf16x8 cvt8(const float* p, int off) {
  float4 a = *reinterpret_cast<const float4*>(p + off);
  float4 b = *reinterpret_cast<const float4*>(p + off + 4);
  bf16x8 v;
  v[0] = (__bf16)a.x; v[1] = (__bf16)a.y; v[2] = (__bf16)a.z; v[3] = (__bf16)a.w;
  v[4] = (__bf16)b.x; v[5] = (__bf16)b.y; v[6] = (__bf16)b.z; v[7] = (__bf16)b.w;
  return v;
}

// ---------------------------------------------------------------------------
// K1: fused prelude. blk < NTILES: keys tile via MFMA (Wk read f32 with
// inline bf16 convert — L2-resident, no separate cvt kernel), output in
// FRAGMENT ORDER via LDS repack. blk >= NTILES: query rows via MFMA,
// row-major bf16 output.
// ---------------------------------------------------------------------------
__global__ __launch_bounds__(64) void k_prep(const float* __restrict__ states,
                                             const float* __restrict__ Wk,
                                             const float* __restrict__ bk,
                                             const float* __restrict__ hidden,
                                             const float* __restrict__ Wq,
                                             const float* __restrict__ bq,
                                             bf16x8* __restrict__ keysF,
                                             __hip_bfloat16* __restrict__ query) {
  __shared__ __align__(16) __hip_bfloat16 sT[16 * STR];
  const int lane = threadIdx.x;
  const int c = lane & 15, hi = lane >> 4;
  int blk = blockIdx.x;

  if (blk >= NTILES) {
    // ---- query path: 16 b rows, D = Wq * hidden^T (+bq)
    const int b0 = (blk - NTILES) * 16;
    bf16x8 hb[2];
    const float* hrow = hidden + (size_t)(b0 + c) * CDIM;
#pragma unroll
    for (int kf = 0; kf < 2; ++kf) hb[kf] = cvt8(hrow, kf * 32 + hi * 8);
#pragma unroll
    for (int ct = 0; ct < 8; ++ct) {
      const float* wrow = Wq + (size_t)(ct * 16 + c) * CDIM;
      f32x4 acc = {};
#pragma unroll
      for (int kf = 0; kf < 2; ++kf)
        acc = __builtin_amdgcn_mfma_f32_16x16x32_bf16(cvt8(wrow, kf * 32 + hi * 8),
                                                      hb[kf], acc, 0, 0, 0);
      float4 bias = *reinterpret_cast<const float4*>(bq + ct * 16 + hi * 4);
      __hip_bfloat16 hv[4];
      hv[0] = __float2bfloat16(acc[0] + bias.x);
      hv[1] = __float2bfloat16(acc[1] + bias.y);
      hv[2] = __float2bfloat16(acc[2] + bias.z);
      hv[3] = __float2bfloat16(acc[3] + bias.w);
      unsigned long long bits;
      __builtin_memcpy(&bits, hv, 8);
      *reinterpret_cast<unsigned long long*>(&sT[c * STR + ct * 16 + 4 * hi]) = bits;
    }
#pragma unroll
    for (int kf = 0; kf < 4; ++kf) {
      bf16x8 v = *reinterpret_cast<const bf16x8*>(&sT[c * STR + kf * 32 + hi * 8]);
      *reinterpret_cast<bf16x8*>(query + (size_t)(b0 + c) * MDIM + kf * 32 + hi * 8) = v;
    }
    return;
  }

  // ---- keys path
  int d, t;
  if      (blk < 2)   { d = blk; t = 0; }
  else if (blk < 6)   { d = 2; t = blk - 2; }
  else if (blk < 22)  { d = 3; t = blk - 6; }
  else if (blk < 86)  { d = 4; t = blk - 22; }
  else if (blk < 342) { d = 5; t = blk - 86; }
  else                { d = 6; t = blk - 342; }
  const int cumArr[7] = {0, 4, 20, 84, 340, 1364, 5460};
  const int k0 = cumArr[d] + 16 * t;

  bf16x8 sb[4];
  const float* srow = states + (size_t)(k0 + c) * MDIM;
#pragma unroll
  for (int kf = 0; kf < 4; ++kf) sb[kf] = cvt8(srow, kf * 32 + hi * 8);

  const float* wkd = Wk + (size_t)d * MDIM * MDIM;
  const float* bkd = bk + d * MDIM;

#pragma unroll
  for (int ct = 0; ct < 8; ++ct) {
    const float* wrow = wkd + (size_t)(ct * 16 + c) * MDIM;
    f32x4 acc = {};
#pragma unroll
    for (int kf = 0; kf < 4; ++kf)
      acc = __builtin_amdgcn_mfma_f32_16x16x32_bf16(cvt8(wrow, kf * 32 + hi * 8),
                                                    sb[kf], acc, 0, 0, 0);
    float4 bias = *reinterpret_cast<const float4*>(bkd + ct * 16 + hi * 4);
    __hip_bfloat16 hv[4];
    hv[0] = __float2bfloat16(fmaxf(acc[0] + bias.x, 0.f));
    hv[1] = __float2bfloat16(fmaxf(acc[1] + bias.y, 0.f));
    hv[2] = __float2bfloat16(fmaxf(acc[2] + bias.z, 0.f));
    hv[3] = __float2bfloat16(fmaxf(acc[3] + bias.w, 0.f));
    unsigned long long bits;
    __builtin_memcpy(&bits, hv, 8);
    *reinterpret_cast<unsigned long long*>(&sT[c * STR + ct * 16 + 4 * hi]) = bits;
  }

#pragma unroll
  for (int kf = 0; kf < 4; ++kf) {
    bf16x8 v = *reinterpret_cast<const bf16x8*>(&sT[c * STR + kf * 32 + hi * 8]);
    keysF[(size_t)(blk * 4 + kf) * 64 + lane] = v;   // 64 lanes x 16B = 1KB
  }
}

// ---------------------------------------------------------------------------
// K3: subtree walker — v13 structure (best measured): wave = one subtree
// (S5) x 32 b, barrier-free, frag-ordered keys straight to registers with
// register ping-pong prefetch, no-max softmax, shuffle parent gather,
// d6+d7 through per-wave LDS transpose buffers flushed as 256B full-line
// runs; d1-d5 direct (d5 buffering measured net-negative in r14).
// ---------------------------------------------------------------------------
#define D7STR 68   // padded row stride (floats)

struct Frag { bf16x8 f[4]; };

__device__ __forceinline__ void load_frags(const bf16x8* __restrict__ kF,
                                           int blk, Frag& fr, int lane) {
#pragma unroll
  for (int kf = 0; kf < 4; ++kf)
    fr.f[kf] = kF[(size_t)(blk * 4 + kf) * 64 + lane];
}

__device__ __forceinline__ float gather_par(const f32x4 cp, int u, int lane) {
  const int src = u * 16 + (lane & 15);
  const float g0 = __shfl(cp[0], src, 64);
  const float g1 = __shfl(cp[1], src, 64);
  const float g2 = __shfl(cp[2], src, 64);
  const float g3 = __shfl(cp[3], src, 64);
  const int hi = lane >> 4;
  const float p01 = (hi & 1) ? g1 : g0;
  const float p23 = (hi & 1) ? g3 : g2;
  return (hi & 2) ? p23 : p01;
}

__device__ __forceinline__ void tile_step(
    const bf16x8* __restrict__ kF, const Frag& cur, int nextBlk, Frag& nxt,
    const bf16x8 (&qf)[2][4], const f32x4* cumPrev, int u, f32x4 (&cumOut)[2],
    float* __restrict__ oPtr, size_t span, bool doStore, bool d1mask,
    float* __restrict__ ldsDst, int lane) {
  const int c = lane & 15, hi = lane >> 4;

  // prefetch next tile's frags (L2 latency hides under this tile's compute)
  if (nextBlk >= 0) load_frags(kF, nextBlk, nxt, lane);

#pragma unroll
  for (int bt = 0; bt < 2; ++bt) {
    f32x4 acc = {};
    acc = __builtin_amdgcn_mfma_f32_16x16x32_bf16(cur.f[0], qf[bt][0], acc, 0, 0, 0);
    acc = __builtin_amdgcn_mfma_f32_16x16x32_bf16(cur.f[1], qf[bt][1], acc, 0, 0, 0);
    acc = __builtin_amdgcn_mfma_f32_16x16x32_bf16(cur.f[2], qf[bt][2], acc, 0, 0, 0);
    acc = __builtin_amdgcn_mfma_f32_16x16x32_bf16(cur.f[3], qf[bt][3], acc, 0, 0, 0);

    // group-of-4 log-softmax without max-subtraction (scores bounded)
    const float lse = __logf(__expf(acc[0]) + __expf(acc[1]) +
                             __expf(acc[2]) + __expf(acc[3]));
    float par = 0.f;
    if (cumPrev) par = gather_par(cumPrev[bt], u, lane);
    f32x4 cm;
    cm[0] = acc[0] - lse + par;
    cm[1] = acc[1] - lse + par;
    cm[2] = acc[2] - lse + par;
    cm[3] = acc[3] - lse + par;
    cumOut[bt] = cm;

    if (ldsDst) {
      *reinterpret_cast<f32x4*>(ldsDst + (bt * 16 + c) * D7STR) = cm;
    } else if (doStore && (!d1mask || hi == 0)) {
      float4 o;
      o.x = cm[0]; o.y = cm[1]; o.z = cm[2]; o.w = cm[3];
      *reinterpret_cast<float4*>(oPtr + (size_t)(bt * 16 + c) * span + hi * 4) = o;
    }
  }
}

__global__ __launch_bounds__(256) void k_tree(const bf16x8* __restrict__ kF,
                                              const __hip_bfloat16* __restrict__ query,
                                              float* __restrict__ out, int B) {
  __shared__ __align__(16) float sD7[4][32 * D7STR]; // per-wave d7 group buffer
  __shared__ __align__(16) float sD6[4][32 * D7STR]; // per-wave d6 subtree buffer

  const int tid  = threadIdx.x;
  const int lane = tid & 63;
  const int w    = tid >> 6;
  const int c    = lane & 15, hi = lane >> 4;

  const int S5  = blockIdx.x & 63;        // depth-5 subtree (XCD = S5%8)
  const int bg  = blockIdx.x >> 6;        // batch group (128 b per block)
  const int T4  = S5 >> 2;
  const int T3  = S5 >> 4;
  const int b0w = bg * 128 + w * 32;      // wave's 32-b base

  float* d7w = &sD7[w][0];
  float* d6w = &sD6[w][0];

  // query B-frags for both b-tiles (held in regs for all tiles)
  bf16x8 qf[2][4];
#pragma unroll
  for (int bt = 0; bt < 2; ++bt) {
    const __hip_bfloat16* qrow = query + (size_t)(b0w + bt * 16 + c) * MDIM;
#pragma unroll
    for (int kf = 0; kf < 4; ++kf)
      qf[bt][kf] = *reinterpret_cast<const bf16x8*>(qrow + kf * 32 + hi * 8);
  }

  Frag fA, fB;
  load_frags(kF, 0, fA, lane);            // d1 tile

  f32x4 c1[2], c2[2], c3[2], c4[2], c5[2], c6[2], c7[2];

  // d1 (blk 0): next d2 (blk 1)
  tile_step(kF, fA, 1, fB, qf, nullptr, 0, c1,
            out + (size_t)b0w * 4, 4, S5 == 0, true, nullptr, lane);
  // d2: next d3
  tile_step(kF, fB, 2 + T3, fA, qf, c1, 0, c2,
            out + (size_t)4 * B + (size_t)b0w * 16, 16, S5 == 0, false,
            nullptr, lane);
  // d3: next d4
  tile_step(kF, fA, 6 + T4, fB, qf, c2, T3, c3,
            out + (size_t)20 * B + (size_t)b0w * 64 + 16 * T3, 64,
            (S5 & 15) == 0, false, nullptr, lane);
  // d4: next d5
  tile_step(kF, fB, 22 + S5, fA, qf, c3, T4 & 3, c4,
            out + (size_t)84 * B + (size_t)b0w * 256 + 16 * T4, 256,
            (S5 & 3) == 0, false, nullptr, lane);
  // d5: next d6(u5=0)
  tile_step(kF, fA, 86 + 4 * S5, fB, qf, c4, S5 & 3, c5,
            out + (size_t)340 * B + (size_t)b0w * 1024 + 16 * S5, 1024,
            true, false, nullptr, lane);

  // d6/d7 groups. Each group = 5 tile_steps; frag parity flips per group.
#pragma unroll
  for (int u5p = 0; u5p < 2; ++u5p) {
#pragma unroll
    for (int half = 0; half < 2; ++half) {
      const int u5 = u5p * 2 + half;
      Frag& f0 = (half == 0) ? fB : fA;   // compile-time after unroll
      Frag& f1 = (half == 0) ? fA : fB;
      const int T6 = 4 * S5 + u5;
      const int d7b = 342 + 16 * S5 + 4 * u5;   // first d7 blk of this group
      // d6: buffered in sD6 (col u5*16), flushed after the u5 loop
      tile_step(kF, f0, d7b, f1, qf, c5, u5, c6,
                nullptr, 0, false, false, d6w + u5 * 16 + hi * 4, lane);
      // d7 u6=0..3
      tile_step(kF, f1, d7b + 1, f0, qf, c6, 0, c7,
                nullptr, 0, false, false, d7w + 0 * 16 + hi * 4, lane);
      tile_step(kF, f0, d7b + 2, f1, qf, c6, 1, c7,
                nullptr, 0, false, false, d7w + 1 * 16 + hi * 4, lane);
      tile_step(kF, f1, d7b + 3, f0, qf, c6, 2, c7,
                nullptr, 0, false, false, d7w + 2 * 16 + hi * 4, lane);
      tile_step(kF, f0, (u5 < 3) ? (86 + 4 * S5 + u5 + 1) : -1, f1, qf, c6, 3, c7,
                nullptr, 0, false, false, d7w + 3 * 16 + hi * 4, lane);
      // flush d6-group T6's d7: 32 b-rows; 8 instrs x 4 rows x 256B runs
      {
        float* dst = out + (size_t)5460 * B + (size_t)b0w * 16384 + 64 * T6;
#pragma unroll
        for (int j = 0; j < 8; ++j) {
          const int r = j * 4 + hi;
          f32x4 v = *reinterpret_cast<const f32x4*>(d7w + r * D7STR + c * 4);
          float4 o;
          o.x = v[0]; o.y = v[1]; o.z = v[2]; o.w = v[3];
          *reinterpret_cast<float4*>(dst + (size_t)r * 16384 + c * 4) = o;
        }
      }
    }
  }

  // flush d6 for the whole subtree: 32 b-rows x 64 keys; 8 instrs x 256B runs
  {
    float* dst = out + (size_t)1364 * B + (size_t)b0w * 4096 + 64 * S5;
#pragma unroll
    for (int j = 0; j < 8; ++j) {
      const int r = j * 4 + hi;
      f32x4 v = *reinterpret_cast<const f32x4*>(d6w + r * D7STR + c * 4);
      float4 o;
      o.x = v[0]; o.y = v[1]; o.z = v[2]; o.w = v[3];
      *reinterpret_cast<float4*>(dst + (size_t)r * 4096 + c * 4) = o;
    }
  }
}

// ---------------------------------------------------------------------------
extern "C" void kernel_launch(void* const* d_in, const int* in_sizes, int n_in,
                              void* d_out, int out_size, void* d_ws, size_t ws_size,
                              hipStream_t stream) {
  const float* hidden = (const float*)d_in[0];
  const float* Wq     = (const float*)d_in[1];
  const float* bq     = (const float*)d_in[2];
  const float* states = (const float*)d_in[3];
  const float* Wk     = (const float*)d_in[4];
  const float* bk     = (const float*)d_in[5];
  float* out = (float*)d_out;
  const int B = in_sizes[0] / CDIM;  // 4096

  __hip_bfloat16* base  = (__hip_bfloat16*)d_ws;
  bf16x8* keysF = (bf16x8*)base;                              // 5.6MB frag-ordered
  __hip_bfloat16* query = base + (size_t)NTILES * 4 * 64 * 8; // B*128 bf16

  // fused prelude: 1366 key tiles + 256 query tiles in one launch
  k_prep<<<NTILES + B / 16, 64, 0, stream>>>(states, Wk, bk, hidden, Wq, bq,
                                             keysF, query);

  // grid: subtree-fastest (XCD pinning): 64 subtrees x B/128 batch groups
  k_tree<<<(B / 128) * 64, 256, 0, stream>>>(keysF, query, out, B);
}